// Round 2
// baseline (35.500 us; speedup 1.0000x reference)
//
#include <hip/hip_runtime.h>
#include <math.h>

// Problem constants (from reference): B=16, T=4096, C=80, K=32
#define CC 80
#define KK 32
#define SST 33                        // 32 sorted entries + 1 sentinel per channel
#define NTOT (16 * 4096 * 80)         // 5,242,880 elements
#define BLOCK 320                     // 5 waves; 320 = 4 * 80 -> exact channel tiling
#define CHUNK 5120                    // 64 * 80 elements per block (20,480 B)
#define GRID (NTOT / CHUNK)           // 1024 blocks, exact
#define EPT (CHUNK / BLOCK)           // 16 elements per thread
#define TBL (CC * SST)                // 2640 entries per table

// ---------------------------------------------------------------------------
// Prep: stable rank-sort each channel's 32 centroids (value asc, orig index
// breaks ties). Writes gv[80][33] (values, +inf sentinel) and gi[80][33]
// (original k, INT_MAX sentinel) into workspace. 2560 threads, ~1 us.
// ---------------------------------------------------------------------------
__global__ void prep_kernel(const float* __restrict__ cent,
                            float* __restrict__ gv,
                            int* __restrict__ gi) {
    const int t = blockIdx.x * blockDim.x + threadIdx.x;
    if (t >= CC * KK) return;
    const int c = t >> 5, k = t & 31;
    const float* row = cent + c * KK;
    const float v = row[k];
    int rank = 0;
#pragma unroll
    for (int j = 0; j < KK; ++j) {
        const float w = row[j];
        // stable: strictly smaller value, or equal value with smaller index
        rank += (int)(w < v) | ((int)(w == v) & (int)(j < k));
    }
    gv[c * SST + rank] = v;
    gi[c * SST + rank] = k;
    if (k == 0) {
        gv[c * SST + 32] = INFINITY;     // sentinel: never wins the final compare
        gi[c * SST + 32] = 0x7fffffff;
    }
}

// ---------------------------------------------------------------------------
// Main: LDS-transpose structure. Global traffic is 100% float4 (16B/lane):
//   stage 5120-elem chunk to LDS -> each thread owns fixed channel c = t % 80,
//   scans its 32 register-resident sorted values (exact one-level count, same
//   arithmetic as the verified previous kernel), fetches the bracketing
//   (value, idx) pair from LDS, resolves with jnp.argmin's first-index
//   tie-break, writes result IN PLACE in LDS, then float4-stores the chunk.
// In-place is race-free: each thread reads and writes only slots t + 320m.
// LDS banks: chunk accesses are lane-consecutive words (conflict-free); pair
// fetch bank = (c + lo) % 32 with stride-1 c across lanes (fully spread).
// ---------------------------------------------------------------------------
__global__ __launch_bounds__(BLOCK) void discretize_kernel(
    const float4* __restrict__ mel4,
    const float* __restrict__ gt,      // gv (2640 f32) then gi (2640 i32)
    float4* __restrict__ out4) {
    __shared__ alignas(16) float tbl[TBL * 2];    // 21,120 B: values then idx
    __shared__ alignas(16) float chunk[CHUNK];    // 20,480 B

    const int t = threadIdx.x;
    const int cb4 = blockIdx.x * (CHUNK / 4);     // chunk base in float4 units

    // Stage sorted tables (1320 x 16B) and input chunk (1280 x 16B), coalesced.
    {
        const ulong2* s = (const ulong2*)gt;
        ulong2* d = (ulong2*)tbl;
        for (int i = t; i < (TBL * 2) / 4; i += BLOCK) d[i] = s[i];
        float4* c4 = (float4*)chunk;
#pragma unroll
        for (int i = 0; i < CHUNK / 4 / BLOCK; ++i)
            c4[t + i * BLOCK] = mel4[cb4 + t + i * BLOCK];
    }
    __syncthreads();

    const float* tv = tbl;
    const int* ti = (const int*)(tbl + TBL);
    const int c = t % CC;                // fixed channel for all 16 elements
    const float* vr = tv + c * SST;
    const int* ir = ti + c * SST;

    // Sorted values into VGPRs (static indices -> registers).
    float sv[KK];
#pragma unroll
    for (int k = 0; k < KK; ++k) sv[k] = vr[k];

#pragma unroll
    for (int m = 0; m < EPT; ++m) {
        const float x = chunk[t + m * BLOCK];

        // insertion count: #{ sorted values <= x }, two parallel chains
        int cA = 0, cB = 0;
#pragma unroll
        for (int k = 0; k < KK; k += 2) {
            cA += (int)(sv[k]     <= x);
            cB += (int)(sv[k + 1] <= x);
        }
        int lo = cA + cB - 1;
        lo = lo < 0 ? 0 : lo;            // cnt==0 -> pair (s0, s1): s0 wins exactly

        // bracketing pair (lo, lo+1); lo+1 == 32 hits the +inf sentinel
        const float vlo = vr[lo], vhi = vr[lo + 1];
        const int ilo = ir[lo], ihi = ir[lo + 1];

        const float dlo = fabsf(x - vlo), dhi = fabsf(x - vhi);
        // strict <, plus first-original-index wins on exact fl-distance tie
        const bool hi = (dhi < dlo) | ((dhi == dlo) & (ihi < ilo));
        chunk[t + m * BLOCK] = hi ? vhi : vlo;   // in place, own slot only
    }
    __syncthreads();

    // Coalesced float4 store of the finished chunk.
    {
        const float4* c4 = (const float4*)chunk;
#pragma unroll
        for (int i = 0; i < CHUNK / 4 / BLOCK; ++i)
            out4[cb4 + t + i * BLOCK] = c4[t + i * BLOCK];
    }
}

extern "C" void kernel_launch(void* const* d_in, const int* in_sizes, int n_in,
                              void* d_out, int out_size, void* d_ws, size_t ws_size,
                              hipStream_t stream) {
    const float* mel = (const float*)d_in[0];   // (B,T,C) f32
    const float* cent = (const float*)d_in[1];  // (C,K) f32
    float* out = (float*)d_out;                 // (B,T,C) f32
    float* gv = (float*)d_ws;                   // 2640 f32
    int* gi = (int*)((float*)d_ws + TBL);       // 2640 i32 (contiguous after gv)

    prep_kernel<<<(CC * KK + 255) / 256, 256, 0, stream>>>(cent, gv, gi);
    discretize_kernel<<<GRID, BLOCK, 0, stream>>>((const float4*)mel, gv,
                                                  (float4*)out);
}

// Round 3
// 30.464 us; speedup vs baseline: 1.1653x; 1.1653x over previous
//
#include <hip/hip_runtime.h>
#include <math.h>

// Problem constants (from reference): B=16, T=4096, C=80, K=32
#define CC 80
#define KK 32
#define SST 33                        // 32 sorted entries + 1 sentinel per channel
#define NTOT (16 * 4096 * 80)         // 5,242,880 elements
#define BLOCK 640                     // 10 waves; 2 blocks/CU exactly (GRID=512)
#define GRID 512
#define NTHREADS (GRID * BLOCK)       // 327,680 = 4096*80 -> %80==0, EPT exact
#define EPT 16

// Sorted centroid entry: value + original k (exact first-index tie-break).
struct Entry { float v; int idx; };

// ---------------------------------------------------------------------------
// Single fused kernel.
//   1) issue all 16 mel loads into registers (latency hides under prep)
//   2) stage centroids to LDS (one float4 per thread, coalesced)
//   3) per-block stable rank-sort (4 entries/thread, broadcast LDS reads)
//   4) per-element: insertion count over 32 register-resident sorted values
//      (two short add chains), fetch bracketing (value,idx) pair from LDS,
//      exact distance compare with jnp.argmin's first-index tie-break.
// Same main-loop arithmetic as the verified round-1 kernel -> absmax 0.0.
// ---------------------------------------------------------------------------
__global__ __launch_bounds__(BLOCK, 5) void discretize_kernel(
    const float* __restrict__ mel,
    const float* __restrict__ cent,
    float* __restrict__ out) {
    __shared__ alignas(16) float scent[CC * KK];   // 10,240 B raw centroids
    __shared__ alignas(16) Entry tab[CC * SST];    // 21,120 B sorted tables

    const int t = threadIdx.x;
    const int tid = blockIdx.x * BLOCK + t;

    // --- 1) prefetch all inputs into registers (coalesced dword loads) ----
    float xr[EPT];
#pragma unroll
    for (int i = 0; i < EPT; ++i) xr[i] = mel[tid + i * NTHREADS];

    // --- 2) stage centroids: 2560 f32 = 640 float4 = exactly 1/thread ----
    ((float4*)scent)[t] = ((const float4*)cent)[t];
    __syncthreads();

    // --- 3) stable rank-sort: entries t, t+640, t+1280, t+1920 ------------
    // Lanes of a half-wave share c -> row reads are LDS broadcasts.
#pragma unroll
    for (int jj = 0; jj < 4; ++jj) {
        const int j = t + jj * BLOCK;
        const int c0 = j >> 5, k0 = j & 31;
        const float* row = scent + c0 * KK;
        const float v = row[k0];
        int rank = 0;
#pragma unroll
        for (int q = 0; q < KK; ++q) {
            const float w = row[q];
            // stable: strictly smaller value, or equal value w/ smaller index
            rank += (int)(w < v) | ((int)(w == v) & (int)(q < k0));
        }
        tab[c0 * SST + rank].v = v;      // rank is a bijection per channel
        tab[c0 * SST + rank].idx = k0;
    }
    if (t < CC) {                        // +inf sentinel: never wins
        tab[t * SST + 32].v = INFINITY;
        tab[t * SST + 32].idx = 0x7fffffff;
    }
    __syncthreads();

    // --- 4) main loop: fixed channel per thread -------------------------
    const int c = tid % CC;
    const Entry* ch = tab + c * SST;

    float sv[KK];                        // sorted values -> VGPRs
#pragma unroll
    for (int k = 0; k < KK; ++k) sv[k] = ch[k].v;

#pragma unroll
    for (int i = 0; i < EPT; ++i) {
        const float x = xr[i];

        // insertion count: #{ sorted values <= x }, two parallel chains
        int cA = 0, cB = 0;
#pragma unroll
        for (int k = 0; k < KK; k += 2) {
            cA += (int)(sv[k]     <= x);
            cB += (int)(sv[k + 1] <= x);
        }
        int lo = cA + cB - 1;
        lo = lo < 0 ? 0 : lo;            // cnt==0 -> pair (s0,s1): s0 wins exactly

        // bracketing pair (lo, lo+1); lo+1 == 32 hits the +inf sentinel
        const Entry e0 = ch[lo];
        const Entry e1 = ch[lo + 1];

        const float dlo = fabsf(x - e0.v), dhi = fabsf(x - e1.v);
        // strict <, plus first-original-index wins on exact fl-distance tie
        const bool hi = (dhi < dlo) | ((dhi == dlo) & (e1.idx < e0.idx));
        out[tid + i * NTHREADS] = hi ? e1.v : e0.v;
    }
}

extern "C" void kernel_launch(void* const* d_in, const int* in_sizes, int n_in,
                              void* d_out, int out_size, void* d_ws, size_t ws_size,
                              hipStream_t stream) {
    const float* mel = (const float*)d_in[0];   // (B,T,C) f32
    const float* cent = (const float*)d_in[1];  // (C,K) f32
    float* out = (float*)d_out;                 // (B,T,C) f32
    discretize_kernel<<<GRID, BLOCK, 0, stream>>>(mel, cent, out);
}

// Round 4
// 28.346 us; speedup vs baseline: 1.2524x; 1.0747x over previous
//
#include <hip/hip_runtime.h>
#include <math.h>

// Problem constants (from reference): B=16, T=4096, C=80, K=32
#define CC 80
#define KK 32
#define SST 33                        // 32 sorted entries + 1 sentinel per channel
#define NTOT (16 * 4096 * 80)         // 5,242,880 elements
#define NP (NTOT / 2)                 // 2,621,440 float2 pairs
#define BLOCK 256
#define GRID 1280                     // 5 blocks/CU nominal
#define NTHREADS (GRID * BLOCK)       // 327,680 ; % 40 == 0 -> fixed channel pair
#define EPTP (NP / NTHREADS)          // 8 pairs (16 elements) per thread, exact

// Sorted centroid entry: value + group-min original k (exact first-index
// tie-break, robust even under duplicate centroid values).
struct Entry { float v; int idx; };

// ---------------------------------------------------------------------------
// Prep: stable rank-sort each channel's 32 centroids. idx stored per slot is
// the MINIMUM original index among centroids equal to that value, so the main
// kernel's midpoint-tie compare reproduces jnp.argmin's first-index rule
// exactly. Sentinel [32] = +inf never wins. 2560 threads, ~1 us.
// ---------------------------------------------------------------------------
__global__ void prep_kernel(const float* __restrict__ cent,
                            Entry* __restrict__ es) {
    const int t = blockIdx.x * blockDim.x + threadIdx.x;
    if (t >= CC * KK) return;
    const int c = t >> 5, k = t & 31;
    const float* row = cent + c * KK;
    const float v = row[k];
    int rank = 0, minidx = k;
#pragma unroll
    for (int j = 0; j < KK; ++j) {
        const float w = row[j];
        // stable: strictly smaller value, or equal value with smaller index
        rank += (int)(w < v) | ((int)(w == v) & (int)(j < k));
        minidx = ((w == v) & (j < minidx)) ? j : minidx;
    }
    es[c * SST + rank].v = v;
    es[c * SST + rank].idx = minidx;
    if (k == 0) {
        es[c * SST + 32].v = INFINITY;
        es[c * SST + 32].idx = 0x7fffffff;
    }
}

// ---------------------------------------------------------------------------
// Main: channel-PAIR per thread -> all global traffic is float2 (8B/lane,
// coalesced, half the memory instructions of the scalar version). Thread
// j = tid % 40 owns channels (2j, 2j+1); both channels' sorted values live in
// VGPRs (64 regs). Per element: insertion count (four independent 16-deep
// cmp+add chains across the pair), bracketing (value,idx) fetch from LDS,
// exact distance compare with jnp.argmin's first-index tie-break.
// Same per-element arithmetic as the verified round-1 kernel -> absmax 0.0.
// ---------------------------------------------------------------------------
__global__ __launch_bounds__(BLOCK, 4) void discretize_kernel(
    const float2* __restrict__ mel2,
    const Entry* __restrict__ es,
    float2* __restrict__ out2) {
    __shared__ alignas(16) Entry tab[CC * SST];   // 21,120 B

    const int t = threadIdx.x;
    // Stage sorted tables: 1320 x 16B, coalesced (L2-resident source).
    {
        const ulong2* s = (const ulong2*)es;
        ulong2* d = (ulong2*)tab;
        for (int i = t; i < (CC * SST) / 2; i += BLOCK) d[i] = s[i];
    }
    __syncthreads();

    const int tid = blockIdx.x * BLOCK + t;
    const int j = tid % 40;                 // fixed channel pair (2j, 2j+1)
    const Entry* ch0 = tab + (2 * j) * SST;
    const Entry* ch1 = tab + (2 * j + 1) * SST;

    // Both channels' sorted values into VGPRs (static indices -> registers).
    float sv0[KK], sv1[KK];
#pragma unroll
    for (int k = 0; k < KK; ++k) { sv0[k] = ch0[k].v; sv1[k] = ch1[k].v; }

#pragma unroll
    for (int i = 0; i < EPTP; ++i) {
        const int p = tid + i * NTHREADS;
        const float2 x = mel2[p];

        // insertion counts: four independent 16-deep chains
        int a0 = 0, b0 = 0, a1 = 0, b1 = 0;
#pragma unroll
        for (int k = 0; k < KK; k += 2) {
            a0 += (int)(sv0[k]     <= x.x);
            b0 += (int)(sv0[k + 1] <= x.x);
            a1 += (int)(sv1[k]     <= x.y);
            b1 += (int)(sv1[k + 1] <= x.y);
        }
        int lo0 = a0 + b0 - 1; lo0 = lo0 < 0 ? 0 : lo0;
        int lo1 = a1 + b1 - 1; lo1 = lo1 < 0 ? 0 : lo1;

        // bracketing pairs; slot 32 is the +inf sentinel
        const Entry e00 = ch0[lo0], e01 = ch0[lo0 + 1];
        const Entry e10 = ch1[lo1], e11 = ch1[lo1 + 1];

        const float d00 = fabsf(x.x - e00.v), d01 = fabsf(x.x - e01.v);
        const float d10 = fabsf(x.y - e10.v), d11 = fabsf(x.y - e11.v);
        // strict <, plus first-original-index wins on exact fl-distance tie
        const bool h0 = (d01 < d00) | ((d01 == d00) & (e01.idx < e00.idx));
        const bool h1 = (d11 < d10) | ((d11 == d10) & (e11.idx < e10.idx));

        float2 r;
        r.x = h0 ? e01.v : e00.v;
        r.y = h1 ? e11.v : e10.v;
        out2[p] = r;
    }
}

extern "C" void kernel_launch(void* const* d_in, const int* in_sizes, int n_in,
                              void* d_out, int out_size, void* d_ws, size_t ws_size,
                              hipStream_t stream) {
    const float* mel = (const float*)d_in[0];   // (B,T,C) f32
    const float* cent = (const float*)d_in[1];  // (C,K) f32
    float* out = (float*)d_out;                 // (B,T,C) f32
    Entry* es = (Entry*)d_ws;                   // 80*33*8 = 21,120 B workspace

    prep_kernel<<<(CC * KK + 255) / 256, 256, 0, stream>>>(cent, es);
    discretize_kernel<<<GRID, BLOCK, 0, stream>>>((const float2*)mel, es,
                                                  (float2*)out);
}

// Round 5
// 27.433 us; speedup vs baseline: 1.2940x; 1.0333x over previous
//
#include <hip/hip_runtime.h>
#include <math.h>

// Problem constants (from reference): B=16, T=4096, C=80, K=32
#define CC 80
#define KK 32
#define STRIDE 33                    // 32 sorted entries + 1 sentinel per channel
#define NTOT (16 * 4096 * 80)        // 5,242,880 elements
#define BLOCK 256
#define GRID 1280                    // 1280*256 = 327,680 threads, multiple of 80
#define NTHREADS (GRID * BLOCK)
#define EPT (NTOT / NTHREADS)        // 16 elements per thread, exact, no tail

// Sorted centroid entry: value + original k (for exact first-index tie-break).
struct Entry { float v; int idx; };

// ---------------------------------------------------------------------------
// Prep: stable rank-sort each channel's 32 centroids (value asc, original
// index breaks value ties). idx stored per slot is the MINIMUM original index
// among equal-valued centroids, so the midpoint-tie compare below reproduces
// jnp.argmin's first-index rule exactly even with duplicate centroid values.
// Sentinel [32] = +inf never wins. 2560 threads, ~1 us.
// ---------------------------------------------------------------------------
__global__ void prep_kernel(const float* __restrict__ cent,
                            Entry* __restrict__ es) {
    const int t = blockIdx.x * blockDim.x + threadIdx.x;
    if (t >= CC * KK) return;
    const int c = t >> 5;   // t / 32
    const int k = t & 31;   // t % 32
    const float* row = cent + c * KK;
    const float v = row[k];
    int rank = 0, minidx = k;
#pragma unroll
    for (int j = 0; j < KK; ++j) {
        const float w = row[j];
        // stable: strictly smaller value, or equal value with smaller index
        rank += (int)(w < v) | ((int)(w == v) & (int)(j < k));
        minidx = ((w == v) & (j < minidx)) ? j : minidx;
    }
    es[c * STRIDE + rank].v = v;
    es[c * STRIDE + rank].idx = minidx;
    if (k == 0) {
        es[c * STRIDE + 32].v = INFINITY;      // sentinel: never wins
        es[c * STRIDE + 32].idx = 0x7fffffff;
    }
}

// ---------------------------------------------------------------------------
// Main: each thread owns a fixed channel c = tid % 80. Sorted values live in
// VGPRs; per element, count how many sorted values are <= x (two independent
// add chains -> short dependence depth), then fetch the two bracketing
// (value, orig_idx) entries from LDS and do the exact distance compare with
// jnp.argmin's first-index tie-break.
//
// Exactness: fl(|x-c|) is monotone in the real distance on each side of x, so
// the global fl-argmin is one of the two bracketing sorted neighbors; the only
// tie between far-apart values (midpoint tie) is lo-vs-hi and is resolved by
// group-min original index, matching the reference bitwise.
// ---------------------------------------------------------------------------
__global__ __launch_bounds__(BLOCK) void discretize_kernel(
    const float* __restrict__ mel,
    const Entry* __restrict__ es,
    float* __restrict__ out) {
    __shared__ alignas(16) Entry se[CC * STRIDE];   // 2640 * 8B = 21,120 B

    // Stage sorted tables to LDS, 16B per lane, coalesced. 2640*8/16 = 1320.
    const int t = threadIdx.x;
    {
        const ulong2* src = (const ulong2*)es;
        ulong2* dst = (ulong2*)se;
        for (int i = t; i < (CC * STRIDE) / 2; i += BLOCK) dst[i] = src[i];
    }
    __syncthreads();

    const int tid = blockIdx.x * BLOCK + t;
    const int c = tid % CC;           // fixed for all EPT elements of this thread
    const Entry* ch = se + c * STRIDE;

    // Sorted values into VGPRs (static indices -> registers).
    float sv[KK];
#pragma unroll
    for (int k = 0; k < KK; ++k) sv[k] = ch[k].v;

#pragma unroll 4
    for (int i = 0; i < EPT; ++i) {
        const int e = tid + i * NTHREADS;
        const float x = mel[e];

        // insertion count: #{ sorted values <= x }, two parallel chains
        int cA = 0, cB = 0;
#pragma unroll
        for (int k = 0; k < KK; k += 2) {
            cA += (int)(sv[k]     <= x);
            cB += (int)(sv[k + 1] <= x);
        }
        int lo = cA + cB - 1;
        lo = lo < 0 ? 0 : lo;         // cnt==0 -> compare (s0, s1): s0 wins exactly

        // bracketing pair (lo, lo+1); lo+1 <= 32 hits the +inf sentinel
        const Entry e0 = ch[lo];
        const Entry e1 = ch[lo + 1];

        const float dlo = fabsf(x - e0.v);
        const float dhi = fabsf(x - e1.v);
        // strict <, plus first-original-index wins on exact fl-distance tie
        const bool hi = (dhi < dlo) | ((dhi == dlo) & (e1.idx < e0.idx));
        out[e] = hi ? e1.v : e0.v;
    }
}

extern "C" void kernel_launch(void* const* d_in, const int* in_sizes, int n_in,
                              void* d_out, int out_size, void* d_ws, size_t ws_size,
                              hipStream_t stream) {
    const float* mel = (const float*)d_in[0];   // (B,T,C) f32
    const float* cent = (const float*)d_in[1];  // (C,K) f32
    float* out = (float*)d_out;                 // (B,T,C) f32
    Entry* es = (Entry*)d_ws;                   // 80*33*8 = 21,120 B of workspace

    prep_kernel<<<(CC * KK + 255) / 256, 256, 0, stream>>>(cent, es);
    discretize_kernel<<<GRID, BLOCK, 0, stream>>>(mel, es, out);
}